// Round 2
// baseline (499.721 us; speedup 1.0000x reference)
//
#include <hip/hip_runtime.h>
#include <cfloat>
#include <math.h>

#define N_OBJ 8
#define N_PTS 2048
#define KNN   10
#define TOLC  0.01f
#define TPB   128               // k_pairs block: one p per thread
#define PTILE 128
#define NTILE (N_PTS / PTILE)   // 16 tiles per pair

// ---- order-preserving float <-> uint for atomicMin on signed floats ----
__device__ __forceinline__ unsigned int enc_f(float f) {
    unsigned int u = __float_as_uint(f);
    return (u & 0x80000000u) ? ~u : (u | 0x80000000u);
}
__device__ __forceinline__ float dec_f(unsigned int e) {
    unsigned int u = (e & 0x80000000u) ? (e & 0x7fffffffu) : ~e;
    return __uint_as_float(u);
}

// Kernel 1: per-point transform. Each thread redundantly does the 4x4 inverse
// in double (closer to the numpy reference than fp32 adjugate), transforms its
// point, and writes G4=(x,y,z,nx), G2=(ny,nz), SD seed = enc(z).
__global__ void k_transform(const float* __restrict__ pts,
                            const float* __restrict__ T_est,
                            const float* __restrict__ T_plane,
                            float4* __restrict__ G4,
                            float2* __restrict__ G2,
                            unsigned int* __restrict__ SD) {
    int gid = blockIdx.x * blockDim.x + threadIdx.x;
    if (gid >= N_OBJ * N_PTS) return;
    int b = gid >> 11;

    double m[16];
#pragma unroll
    for (int i = 0; i < 16; i++) m[i] = (double)T_plane[i];
    double inv[16];
    inv[0]  =  m[5]*m[10]*m[15] - m[5]*m[11]*m[14] - m[9]*m[6]*m[15] + m[9]*m[7]*m[14] + m[13]*m[6]*m[11] - m[13]*m[7]*m[10];
    inv[4]  = -m[4]*m[10]*m[15] + m[4]*m[11]*m[14] + m[8]*m[6]*m[15] - m[8]*m[7]*m[14] - m[12]*m[6]*m[11] + m[12]*m[7]*m[10];
    inv[8]  =  m[4]*m[9]*m[15]  - m[4]*m[11]*m[13] - m[8]*m[5]*m[15] + m[8]*m[7]*m[13] + m[12]*m[5]*m[11] - m[12]*m[7]*m[9];
    inv[12] = -m[4]*m[9]*m[14]  + m[4]*m[10]*m[13] + m[8]*m[5]*m[14] - m[8]*m[6]*m[13] - m[12]*m[5]*m[10] + m[12]*m[6]*m[9];
    inv[1]  = -m[1]*m[10]*m[15] + m[1]*m[11]*m[14] + m[9]*m[2]*m[15] - m[9]*m[3]*m[14] - m[13]*m[2]*m[11] + m[13]*m[3]*m[10];
    inv[5]  =  m[0]*m[10]*m[15] - m[0]*m[11]*m[14] - m[8]*m[2]*m[15] + m[8]*m[3]*m[14] + m[12]*m[2]*m[11] - m[12]*m[3]*m[10];
    inv[9]  = -m[0]*m[9]*m[15]  + m[0]*m[11]*m[13] + m[8]*m[1]*m[15] - m[8]*m[3]*m[13] - m[12]*m[1]*m[11] + m[12]*m[3]*m[9];
    inv[13] =  m[0]*m[9]*m[14]  - m[0]*m[10]*m[13] - m[8]*m[1]*m[14] + m[8]*m[2]*m[13] + m[12]*m[1]*m[10] - m[12]*m[2]*m[9];
    inv[2]  =  m[1]*m[6]*m[15]  - m[1]*m[7]*m[14]  - m[5]*m[2]*m[15] + m[5]*m[3]*m[14] + m[13]*m[2]*m[7]  - m[13]*m[3]*m[6];
    inv[6]  = -m[0]*m[6]*m[15]  + m[0]*m[7]*m[14]  + m[4]*m[2]*m[15] - m[4]*m[3]*m[14] - m[12]*m[2]*m[7]  + m[12]*m[3]*m[6];
    inv[10] =  m[0]*m[5]*m[15]  - m[0]*m[7]*m[13]  - m[4]*m[1]*m[15] + m[4]*m[3]*m[13] + m[12]*m[1]*m[7]  - m[12]*m[3]*m[5];
    inv[14] = -m[0]*m[5]*m[14]  + m[0]*m[6]*m[13]  + m[4]*m[1]*m[14] - m[4]*m[2]*m[13] - m[12]*m[1]*m[6]  + m[12]*m[2]*m[5];
    inv[3]  = -m[1]*m[6]*m[11]  + m[1]*m[7]*m[10]  + m[5]*m[2]*m[11] - m[5]*m[3]*m[10] - m[9]*m[2]*m[7]   + m[9]*m[3]*m[6];
    inv[7]  =  m[0]*m[6]*m[11]  - m[0]*m[7]*m[10]  - m[4]*m[2]*m[11] + m[4]*m[3]*m[10] + m[8]*m[2]*m[7]   - m[8]*m[3]*m[6];
    inv[11] = -m[0]*m[5]*m[11]  + m[0]*m[7]*m[9]   + m[4]*m[1]*m[11] - m[4]*m[3]*m[9]  - m[8]*m[1]*m[7]   + m[8]*m[3]*m[5];
    inv[15] =  m[0]*m[5]*m[10]  - m[0]*m[6]*m[9]   - m[4]*m[1]*m[10] + m[4]*m[2]*m[9]  + m[8]*m[1]*m[6]   - m[8]*m[2]*m[5];
    double det  = m[0]*inv[0] + m[1]*inv[4] + m[2]*inv[8] + m[3]*inv[12];
    double rdet = 1.0 / det;

    const float* Te = T_est + b * 16;
    double M[12];
#pragma unroll
    for (int i = 0; i < 3; i++)
#pragma unroll
        for (int j = 0; j < 4; j++) {
            double s = 0.0;
#pragma unroll
            for (int kk = 0; kk < 4; kk++) s += inv[i*4+kk] * rdet * (double)Te[kk*4+j];
            M[i*4+j] = s;
        }

    const float* pp = pts + (size_t)gid * 6;
    double px = pp[0], py = pp[1], pz = pp[2];
    float nx = pp[3], ny = pp[4], nz = pp[5];
    float x = (float)(M[0]*px + M[1]*py + M[2]*pz  + M[3]);
    float y = (float)(M[4]*px + M[5]*py + M[6]*pz  + M[7]);
    float z = (float)(M[8]*px + M[9]*py + M[10]*pz + M[11]);
    G4[gid] = make_float4(x, y, z, nx);
    G2[gid] = make_float2(ny, nz);
    SD[gid] = enc_f(z);   // seed min with the plane-distance term z
}

// Kernel 2: one block per (pair, 128-p tile). Object o staged in LDS:
// P4=(x,y,z,nx) 32KB + N2=(ny,nz) 16KB. All lanes scan the same q -> pure
// broadcast, conflict-free. Top-10 kept as an ascending sorted list of
// d2 values with the inside-sign bit packed into the d2 mantissa LSB;
// insert is a 9-deep independent v_med3_f32 chain + v_min (10 VALU ops,
// vs ~56 for index-carrying sorted insert). No indices needed anywhere.
__global__ void __launch_bounds__(TPB) k_pairs(const float4* __restrict__ G4,
                                               const float2* __restrict__ G2,
                                               unsigned int* __restrict__ SD) {
    __shared__ float4 P4[N_PTS];   // 32 KiB
    __shared__ float2 N2[N_PTS];   // 16 KiB
    int bx   = blockIdx.x;
    int pair = bx >> 4;            // / NTILE
    int tile = bx & (NTILE - 1);
    int b  = pair / 7;
    int oi = pair % 7;
    int o  = oi + (oi >= b ? 1 : 0);
    int tid = threadIdx.x;

    for (int i = tid; i < N_PTS; i += TPB) {
        P4[i] = G4[o * N_PTS + i];
        N2[i] = G2[o * N_PTS + i];
    }
    __syncthreads();

    int p = tile * PTILE + tid;
    float4 xp = G4[b * N_PTS + p];

    // ascending top-10 of sign-packed d2; init = FLT_MAX with LSB cleared
    const float FMAXE = __uint_as_float(0x7F7FFFFEu);
    float td[KNN];
#pragma unroll
    for (int j = 0; j < KNN; j++) td[j] = FMAXE;
    float thr = FMAXE;

#pragma unroll 4
    for (int q = 0; q < N_PTS; q++) {
        float4 a = P4[q];
        float dx = a.x - xp.x;
        float dy = a.y - xp.y;
        float dz = a.z - xp.z;
        float c  = fmaf(dx, dx, fmaf(dy, dy, dz * dz));
        if (c < thr) {
            float2 nn = N2[q];
            float s = fmaf(a.w, dx, fmaf(nn.x, dy, nn.y * dz));
            unsigned int cu = (__float_as_uint(c) & 0xFFFFFFFEu) | (s > 0.0f ? 1u : 0u);
            float cp = __uint_as_float(cu);
            // med3 insertion into sorted list (descending j reads originals)
#pragma unroll
            for (int j = KNN - 1; j >= 1; --j)
                td[j] = __builtin_amdgcn_fmed3f(td[j - 1], td[j], cp);
            td[0] = fminf(td[0], cp);
            thr = td[KNN - 1];
        }
    }

    int cnt = 0;
#pragma unroll
    for (int j = 0; j < KNN; j++) cnt += (int)(__float_as_uint(td[j]) & 1u);
    float d2 = __uint_as_float(__float_as_uint(td[0]) & 0xFFFFFFFEu);
    float d0 = sqrtf(fmaxf(d2, 0.0f));
    if (cnt > 8) d0 = -d0;           // sum(insides) > k*0.8 = 8  ->  >= 9
    atomicMin(&SD[b * N_PTS + p], enc_f(d0));
}

// Kernel 3: decode and emit both outputs (signed_distance, then intersects
// as 0.0/1.0 floats).
__global__ void k_final(const unsigned int* __restrict__ SD,
                        float* __restrict__ out) {
    int gid = blockIdx.x * blockDim.x + threadIdx.x;
    if (gid >= N_OBJ * N_PTS) return;
    float sd = dec_f(SD[gid]);
    out[gid] = sd;
    out[N_OBJ * N_PTS + gid] = (sd < -TOLC) ? 1.0f : 0.0f;
}

extern "C" void kernel_launch(void* const* d_in, const int* in_sizes, int n_in,
                              void* d_out, int out_size, void* d_ws, size_t ws_size,
                              hipStream_t stream) {
    const float* pts     = (const float*)d_in[0];   // (8,2048,6)
    const float* T_est   = (const float*)d_in[1];   // (8,4,4)
    const float* T_plane = (const float*)d_in[2];   // (4,4)
    // d_in[3] is k == 10, hardcoded as KNN

    // workspace layout: G4 (256KB) | G2 (128KB) | SD (64KB)
    float4*       G4 = (float4*)d_ws;
    float2*       G2 = (float2*)(G4 + N_OBJ * N_PTS);
    unsigned int* SD = (unsigned int*)(G2 + N_OBJ * N_PTS);

    float* out = (float*)d_out;

    k_transform<<<(N_OBJ * N_PTS) / 256, 256, 0, stream>>>(pts, T_est, T_plane, G4, G2, SD);
    k_pairs<<<N_OBJ * (N_OBJ - 1) * NTILE, TPB, 0, stream>>>(G4, G2, SD);
    k_final<<<(N_OBJ * N_PTS) / 256, 256, 0, stream>>>(SD, out);
}

// Round 3
// 211.286 us; speedup vs baseline: 2.3651x; 2.3651x over previous
//
#include <hip/hip_runtime.h>
#include <cfloat>
#include <math.h>

#define N_OBJ 8
#define N_PTS 2048
#define KNN   10
#define TOLC  0.01f
#define TPB   256
#define NTILE (N_PTS / TPB)   // 8 tiles per pair

// ---- order-preserving float <-> uint for atomicMin on signed floats ----
__device__ __forceinline__ unsigned int enc_f(float f) {
    unsigned int u = __float_as_uint(f);
    return (u & 0x80000000u) ? ~u : (u | 0x80000000u);
}
__device__ __forceinline__ float dec_f(unsigned int e) {
    unsigned int u = (e & 0x80000000u) ? (e & 0x7fffffffu) : ~e;
    return __uint_as_float(u);
}

// Kernel 1: per-point transform (4x4 inverse redundantly in double — closer
// to the numpy reference than fp32 adjugate; trivial cost at 64 waves).
// Writes P4=(x,y,z,|x|^2), N4=(nx,ny,nz,dot(n,x)), SD seed = enc(z).
__global__ void k_transform(const float* __restrict__ pts,
                            const float* __restrict__ T_est,
                            const float* __restrict__ T_plane,
                            float4* __restrict__ P4g,
                            float4* __restrict__ N4g,
                            unsigned int* __restrict__ SD) {
    int gid = blockIdx.x * blockDim.x + threadIdx.x;
    if (gid >= N_OBJ * N_PTS) return;
    int b = gid >> 11;

    double m[16];
#pragma unroll
    for (int i = 0; i < 16; i++) m[i] = (double)T_plane[i];
    double inv[16];
    inv[0]  =  m[5]*m[10]*m[15] - m[5]*m[11]*m[14] - m[9]*m[6]*m[15] + m[9]*m[7]*m[14] + m[13]*m[6]*m[11] - m[13]*m[7]*m[10];
    inv[4]  = -m[4]*m[10]*m[15] + m[4]*m[11]*m[14] + m[8]*m[6]*m[15] - m[8]*m[7]*m[14] - m[12]*m[6]*m[11] + m[12]*m[7]*m[10];
    inv[8]  =  m[4]*m[9]*m[15]  - m[4]*m[11]*m[13] - m[8]*m[5]*m[15] + m[8]*m[7]*m[13] + m[12]*m[5]*m[11] - m[12]*m[7]*m[9];
    inv[12] = -m[4]*m[9]*m[14]  + m[4]*m[10]*m[13] + m[8]*m[5]*m[14] - m[8]*m[6]*m[13] - m[12]*m[5]*m[10] + m[12]*m[6]*m[9];
    inv[1]  = -m[1]*m[10]*m[15] + m[1]*m[11]*m[14] + m[9]*m[2]*m[15] - m[9]*m[3]*m[14] - m[13]*m[2]*m[11] + m[13]*m[3]*m[10];
    inv[5]  =  m[0]*m[10]*m[15] - m[0]*m[11]*m[14] - m[8]*m[2]*m[15] + m[8]*m[3]*m[14] + m[12]*m[2]*m[11] - m[12]*m[3]*m[10];
    inv[9]  = -m[0]*m[9]*m[15]  + m[0]*m[11]*m[13] + m[8]*m[1]*m[15] - m[8]*m[3]*m[13] - m[12]*m[1]*m[11] + m[12]*m[3]*m[9];
    inv[13] =  m[0]*m[9]*m[14]  - m[0]*m[10]*m[13] - m[8]*m[1]*m[14] + m[8]*m[2]*m[13] + m[12]*m[1]*m[10] - m[12]*m[2]*m[9];
    inv[2]  =  m[1]*m[6]*m[15]  - m[1]*m[7]*m[14]  - m[5]*m[2]*m[15] + m[5]*m[3]*m[14] + m[13]*m[2]*m[7]  - m[13]*m[3]*m[6];
    inv[6]  = -m[0]*m[6]*m[15]  + m[0]*m[7]*m[14]  + m[4]*m[2]*m[15] - m[4]*m[3]*m[14] - m[12]*m[2]*m[7]  + m[12]*m[3]*m[6];
    inv[10] =  m[0]*m[5]*m[15]  - m[0]*m[7]*m[13]  - m[4]*m[1]*m[15] + m[4]*m[3]*m[13] + m[12]*m[1]*m[7]  - m[12]*m[3]*m[5];
    inv[14] = -m[0]*m[5]*m[14]  + m[0]*m[6]*m[13]  + m[4]*m[1]*m[14] - m[4]*m[2]*m[13] - m[12]*m[1]*m[6]  + m[12]*m[2]*m[5];
    inv[3]  = -m[1]*m[6]*m[11]  + m[1]*m[7]*m[10]  + m[5]*m[2]*m[11] - m[5]*m[3]*m[10] - m[9]*m[2]*m[7]   + m[9]*m[3]*m[6];
    inv[7]  =  m[0]*m[6]*m[11]  - m[0]*m[7]*m[10]  - m[4]*m[2]*m[11] + m[4]*m[3]*m[10] + m[8]*m[2]*m[7]   - m[8]*m[3]*m[6];
    inv[11] = -m[0]*m[5]*m[11]  + m[0]*m[7]*m[9]   + m[4]*m[1]*m[11] - m[4]*m[3]*m[9]  - m[8]*m[1]*m[7]   + m[8]*m[3]*m[5];
    inv[15] =  m[0]*m[5]*m[10]  - m[0]*m[6]*m[9]   - m[4]*m[1]*m[10] + m[4]*m[2]*m[9]  + m[8]*m[1]*m[6]   - m[8]*m[2]*m[5];
    double det  = m[0]*inv[0] + m[1]*inv[4] + m[2]*inv[8] + m[3]*inv[12];
    double rdet = 1.0 / det;

    const float* Te = T_est + b * 16;
    double M[12];
#pragma unroll
    for (int i = 0; i < 3; i++)
#pragma unroll
        for (int j = 0; j < 4; j++) {
            double s = 0.0;
#pragma unroll
            for (int kk = 0; kk < 4; kk++) s += inv[i*4+kk] * rdet * (double)Te[kk*4+j];
            M[i*4+j] = s;
        }

    const float* pp = pts + (size_t)gid * 6;
    double px = pp[0], py = pp[1], pz = pp[2];
    float nx = pp[3], ny = pp[4], nz = pp[5];
    float x = (float)(M[0]*px + M[1]*py + M[2]*pz  + M[3]);
    float y = (float)(M[4]*px + M[5]*py + M[6]*pz  + M[7]);
    float z = (float)(M[8]*px + M[9]*py + M[10]*pz + M[11]);
    float sq = fmaf(x, x, fmaf(y, y, z * z));
    float w  = fmaf(nx, x, fmaf(ny, y, nz * z));
    P4g[gid] = make_float4(x, y, z, sq);
    N4g[gid] = make_float4(nx, ny, nz, w);
    SD[gid]  = enc_f(z);   // seed min with the plane-distance term z
}

// Kernel 2: one block per (pair, 256-p tile). P-stream of object o staged in
// 32KB LDS (ds_read_b128, lgkmcnt); N-stream read from global per-iteration
// at a wave-uniform address (vmcnt, L1/L2 broadcast) — two independent
// latency counters, so neither wait drains the other. Branchless body:
//   c' = sq_q - 2*dot(xq,xp)        (sq_p added in epilogue; order-invariant)
//   s  = w_q - dot(n_q, xp)         (inside sign, packed into c' LSB)
//   10-deep med3 insertion          (no indices carried)
__global__ void __launch_bounds__(TPB) k_pairs(const float4* __restrict__ P4g,
                                               const float4* __restrict__ N4g,
                                               unsigned int* __restrict__ SD) {
    __shared__ float4 P4[N_PTS];   // 32 KiB
    int bx   = blockIdx.x;
    int pair = bx >> 3;            // / NTILE
    int tile = bx & (NTILE - 1);
    int b  = pair / 7;
    int oi = pair % 7;
    int o  = oi + (oi >= b ? 1 : 0);
    int tid = threadIdx.x;

    for (int i = tid; i < N_PTS; i += TPB) P4[i] = P4g[o * N_PTS + i];
    __syncthreads();

    int p = tile * TPB + tid;
    float4 xp = P4g[b * N_PTS + p];          // (x, y, z, sq_p)
    float mx = -2.0f * xp.x, my = -2.0f * xp.y, mz = -2.0f * xp.z;
    float gx = -xp.x, gy = -xp.y, gz = -xp.z;

    // divergent-looking zero: keeps the N-stream load on the vector memory
    // path (VMEM/vmcnt). If it scalarized to s_load, its results would share
    // lgkmcnt with ds_read and force full-drain waits every iteration.
    int dz0 = (int)__builtin_amdgcn_mbcnt_lo(0u, 0u);
    const float4* No = N4g + o * N_PTS + dz0;

    const float FMAXE = __uint_as_float(0x7F7FFFFEu);   // FLT_MAX, LSB clear
    float td[KNN];
#pragma unroll
    for (int j = 0; j < KNN; j++) td[j] = FMAXE;

#pragma unroll 8
    for (int q = 0; q < N_PTS; q++) {
        float4 a = P4[q];
        float4 n = No[q];
        float c  = fmaf(mx, a.x, fmaf(my, a.y, fmaf(mz, a.z, a.w)));
        float s  = fmaf(n.x, gx, fmaf(n.y, gy, fmaf(n.z, gz, n.w)));
        unsigned int cu = (__float_as_uint(c) & 0xFFFFFFFEu) | (s > 0.0f ? 1u : 0u);
        float cp = __uint_as_float(cu);
#pragma unroll
        for (int j = KNN - 1; j >= 1; --j)
            td[j] = __builtin_amdgcn_fmed3f(td[j - 1], td[j], cp);
        td[0] = fminf(td[0], cp);
    }

    int cnt = 0;
#pragma unroll
    for (int j = 0; j < KNN; j++) cnt += (int)(__float_as_uint(td[j]) & 1u);
    float d2 = __uint_as_float(__float_as_uint(td[0]) & 0xFFFFFFFEu) + xp.w;
    float d0 = sqrtf(fmaxf(d2, 0.0f));
    if (cnt > 8) d0 = -d0;           // sum(insides) > k*0.8 = 8  ->  >= 9
    atomicMin(&SD[b * N_PTS + p], enc_f(d0));
}

// Kernel 3: decode and emit both outputs (signed_distance, then intersects
// as 0.0/1.0 floats).
__global__ void k_final(const unsigned int* __restrict__ SD,
                        float* __restrict__ out) {
    int gid = blockIdx.x * blockDim.x + threadIdx.x;
    if (gid >= N_OBJ * N_PTS) return;
    float sd = dec_f(SD[gid]);
    out[gid] = sd;
    out[N_OBJ * N_PTS + gid] = (sd < -TOLC) ? 1.0f : 0.0f;
}

extern "C" void kernel_launch(void* const* d_in, const int* in_sizes, int n_in,
                              void* d_out, int out_size, void* d_ws, size_t ws_size,
                              hipStream_t stream) {
    const float* pts     = (const float*)d_in[0];   // (8,2048,6)
    const float* T_est   = (const float*)d_in[1];   // (8,4,4)
    const float* T_plane = (const float*)d_in[2];   // (4,4)
    // d_in[3] is k == 10, hardcoded as KNN

    // workspace layout: P4 (256KB) | N4 (256KB) | SD (64KB)
    float4*       P4 = (float4*)d_ws;
    float4*       N4 = P4 + N_OBJ * N_PTS;
    unsigned int* SD = (unsigned int*)(N4 + N_OBJ * N_PTS);

    float* out = (float*)d_out;

    k_transform<<<(N_OBJ * N_PTS) / 256, 256, 0, stream>>>(pts, T_est, T_plane, P4, N4, SD);
    k_pairs<<<N_OBJ * (N_OBJ - 1) * NTILE, TPB, 0, stream>>>(P4, N4, SD);
    k_final<<<(N_OBJ * N_PTS) / 256, 256, 0, stream>>>(SD, out);
}